// Round 9
// baseline (140.683 us; speedup 1.0000x reference)
//
#include <hip/hip_runtime.h>
#include <math.h>

// Problem constants (fixed by setup_inputs)
constexpr int B = 32;
constexpr int N = 65;    // seq_len + 1
constexpr int D = 512;
constexpr int S = 64;    // N - 1
constexpr int M = B * N; // 2080 rows for the QK projection GEMM

constexpr size_t OUT0_ELEMS = (size_t)B * S * (S + 1) * D;       // 68,157,440
constexpr size_t Q_ELEMS    = (size_t)M * D;                      // 1,064,960
constexpr size_t STAGE_BASE = OUT0_ELEMS - 2 * Q_ELEMS;           // b31 start (fallback staging)
constexpr int OUT0_F4 = (int)(OUT0_ELEMS / 4);                    // 17,039,360
constexpr int ROW_F4  = (S + 1) * (D / 4);                        // 8320

// Grids
constexpr int NG_GEMM = 528;   // 33 m-tiles x 8 n-tiles x 2 matrices (R2-proven)
constexpr int NG_FILL = 1536;
constexpr int N3_ROWS = 2048;  // one block per (b,i) output row
constexpr int N3_TAIL = 32;    // one block per batch: leader+member tail

// ---------------------------------------------------------------------------
// A: fused projection GEMM (q = nve@Wq^T+bq row-major; kT[b][d][n]) plus
// zero-fill of out0 [0, nf4). GEMM body is R2's proven 64x64/BK=32 3-tile
// version (26.1 KB LDS -> 6 blocks/CU so fill blocks co-reside).
// ---------------------------------------------------------------------------
__global__ __launch_bounds__(256) void kA_gemm_fill(
    const float* __restrict__ nve, const float* __restrict__ Wq,
    const float* __restrict__ bq, const float* __restrict__ Wk,
    const float* __restrict__ bk, float* __restrict__ q,
    float* __restrict__ kT, float* __restrict__ out, int nf4)
{
    __shared__ float As[32][68];
    __shared__ float Qs[32][68];
    __shared__ float Ks[32][68];

    const int gid = blockIdx.x;
    const int tid = threadIdx.x;

    if (gid < NG_GEMM) {
        const int mat = gid >= (NG_GEMM / 2);
        const int t   = mat ? gid - NG_GEMM / 2 : gid;
        const int bm  = (t % 33) * 64;
        const int bn  = (t / 33) * 64;

        const int tr = tid / 16;
        const int tc = tid % 16;

        float accq[4][4] = {};
        float acck[4][4] = {};

        for (int k0 = 0; k0 < D; k0 += 32) {
            const int r  = tid / 8;
            const int c4 = (tid % 8) * 4;
            #pragma unroll
            for (int p = 0; p < 2; ++p) {
                const int rr = p * 32 + r;
                const int gm = bm + rr;
                float4 v = make_float4(0.f, 0.f, 0.f, 0.f);
                if (gm < M) v = *(const float4*)&nve[(size_t)gm * D + k0 + c4];
                As[c4 + 0][rr] = v.x; As[c4 + 1][rr] = v.y;
                As[c4 + 2][rr] = v.z; As[c4 + 3][rr] = v.w;
            }
            #pragma unroll
            for (int p = 0; p < 2; ++p) {
                const int rr = p * 32 + r;
                const int gn = bn + rr;
                float4 vq = *(const float4*)&Wq[(size_t)gn * D + k0 + c4];
                float4 vk = *(const float4*)&Wk[(size_t)gn * D + k0 + c4];
                Qs[c4 + 0][rr] = vq.x; Qs[c4 + 1][rr] = vq.y;
                Qs[c4 + 2][rr] = vq.z; Qs[c4 + 3][rr] = vq.w;
                Ks[c4 + 0][rr] = vk.x; Ks[c4 + 1][rr] = vk.y;
                Ks[c4 + 2][rr] = vk.z; Ks[c4 + 3][rr] = vk.w;
            }
            __syncthreads();

            #pragma unroll
            for (int kk = 0; kk < 32; ++kk) {
                float a[4], wq_[4], wk_[4];
                #pragma unroll
                for (int u = 0; u < 4; ++u) a[u]   = As[kk][tr * 4 + u];
                #pragma unroll
                for (int u = 0; u < 4; ++u) wq_[u] = Qs[kk][tc * 4 + u];
                #pragma unroll
                for (int u = 0; u < 4; ++u) wk_[u] = Ks[kk][tc * 4 + u];
                #pragma unroll
                for (int i = 0; i < 4; ++i)
                    #pragma unroll
                    for (int j = 0; j < 4; ++j) {
                        accq[i][j] += a[i] * wq_[j];
                        acck[i][j] += a[i] * wk_[j];
                    }
            }
            __syncthreads();
        }

        #pragma unroll
        for (int i = 0; i < 4; ++i) {
            const int gm = bm + tr * 4 + i;
            if (gm >= M) continue;
            const int b = gm / N;
            const int n = gm % N;
            #pragma unroll
            for (int j = 0; j < 4; ++j) {
                const int gd = bn + tc * 4 + j;
                q[(size_t)gm * D + gd] = accq[i][j] + bq[gd];
                kT[(size_t)b * D * N + (size_t)gd * N + n] = acck[i][j] + bk[gd];
            }
        }
    } else {
        const float4 z = make_float4(0.f, 0.f, 0.f, 0.f);
        float4* o4 = (float4*)out;
        const int nthr = NG_FILL * 256;
        for (int f = (gid - NG_GEMM) * 256 + tid; f < nf4; f += nthr)
            o4[f] = z;
    }
}

// ---------------------------------------------------------------------------
// B: attention + membership, R2's proven 1-row-per-block version (2048 x 128;
// 8+ blocks/CU so the 512-iter k-loop latency is TLP-hidden).
// ---------------------------------------------------------------------------
__global__ __launch_bounds__(128) void kB_attn(
    const float* __restrict__ q, const float* __restrict__ kT,
    unsigned long long* __restrict__ mem)
{
    const int bi = blockIdx.x;     // 0..B*S-1
    const int b = bi / S;
    const int r = bi % S;
    const int i = r + 1;
    const int t = threadIdx.x;

    __shared__ float qrow[D];
    __shared__ float sc[N];

    *(float4*)&qrow[t * 4] = *(const float4*)&q[((size_t)b * N + i) * D + t * 4];
    __syncthreads();

    if (t < N) {
        const float* kp = &kT[(size_t)b * D * N];
        float acc = 0.f;
        for (int e = 0; e < D; ++e) acc += qrow[e] * kp[(size_t)e * N + t];
        float s = acc * 0.044194173824159216f;  // 1/sqrt(512)
        if (t == i) s = 0.f;                    // diag of [1:,1:] zeroed pre-softmax
        sc[t] = s;
    }
    __syncthreads();

    if (t < 64) {
        float mx = -INFINITY;
        for (int j = 0; j < N; ++j) mx = fmaxf(mx, sc[j]);
        float sum = 0.f;
        for (int j = 0; j < N; ++j) sum += expf(sc[j] - mx);
        const float p = expf(sc[t + 1] - mx) / sum;
        const bool bit = (p > 0.05f) || (t + 1 == i);
        unsigned long long mask = __ballot(bit);
        if (t == 0) mem[bi] = mask;
    }
}

// ---------------------------------------------------------------------------
// C: fused cluster + scatter + tail. Every block recomputes its batch's
// greedy clustering (verified R5 shfl prologue) from mem — no separate
// cluster kernel, no cross-block dependency.
//   gid < 2048: output row gid. Normally scatter-only (zeros pre-written);
//               if dense31 and row belongs to b=31, gated-dense rewrite
//               (covers the q/kT staging region in fallback mode).
//   gid >= 2048: per-batch leader/member tail (verified R5 body).
// ---------------------------------------------------------------------------
__global__ __launch_bounds__(256) void kC_finish(
    const float* __restrict__ nve, const float* __restrict__ cls,
    const unsigned long long* __restrict__ mem, float* __restrict__ out,
    int dense31)
{
    const int gid = blockIdx.x;
    const int t = threadIdx.x;
    const int b = (gid < N3_ROWS) ? (gid >> 6) : (gid - N3_ROWS);

    __shared__ unsigned long long s_sel[S];
    __shared__ unsigned long long s_lead;

    if (t < 64) {
        const unsigned long long myrow = mem[b * S + t];
        unsigned long long used = 0ull, lb = 0ull, mysel = 0ull;
        for (int i = 0; i < S; ++i) {
            const unsigned long long row = __shfl(myrow, i, 64);
            const bool active = !((used >> i) & 1ull);
            const unsigned long long sl = active ? row : 0ull;
            used |= sl;
            lb |= (unsigned long long)active << i;
            if (t == i) mysel = sl;
        }
        s_sel[t] = mysel;
        if (t == 0) s_lead = lb;
    }
    __syncthreads();

    if (gid < N3_ROWS) {
        const int i = gid & 63;
        const bool dense = dense31 && (gid >= 1984);   // b == 31 rows
        const unsigned long long sb = s_sel[i];
        const bool lbit = (s_lead >> i) & 1ull;
        float4* slot0 = (float4*)(out + (size_t)gid * (S + 1) * D);
        const int h = t >> 7;
        const int tt = t & 127;
        const float4 z = make_float4(0.f, 0.f, 0.f, 0.f);
        for (int s = h; s <= S; s += 2) {
            const bool on = (s == 0) ? lbit : ((sb >> (s - 1)) & 1ull);
            if (on) {
                const float* src = (s == 0) ? cls : &nve[((size_t)b * N + s) * D];
                slot0[(size_t)s * 128 + tt] = ((const float4*)src)[tt];
            } else if (dense) {
                slot0[(size_t)s * 128 + tt] = z;
            }
        }
    } else {
        float* tail = out + OUT0_ELEMS;
        if (t < 16) {   // leader [B,S]: 16 f4 per batch
            float4 v;
            v.x = (float)((s_lead >> (t * 4 + 0)) & 1ull);
            v.y = (float)((s_lead >> (t * 4 + 1)) & 1ull);
            v.z = (float)((s_lead >> (t * 4 + 2)) & 1ull);
            v.w = (float)((s_lead >> (t * 4 + 3)) & 1ull);
            ((float4*)tail)[b * 16 + t] = v;
        }
        // member [B,S,S]: 1024 f4 per batch
        float4* m4 = (float4*)tail + (B * S / 4) + b * (S * S / 4);
        #pragma unroll
        for (int p = 0; p < 4; ++p) {
            const int f  = p * 256 + t;
            const int i  = f >> 4;
            const int j4 = (f & 15) * 4;
            const unsigned long long sr = s_sel[i];
            float4 v;
            v.x = (float)((sr >> (j4 + 0)) & 1ull);
            v.y = (float)((sr >> (j4 + 1)) & 1ull);
            v.z = (float)((sr >> (j4 + 2)) & 1ull);
            v.w = (float)((sr >> (j4 + 3)) & 1ull);
            m4[f] = v;
        }
    }
}

extern "C" void kernel_launch(void* const* d_in, const int* in_sizes, int n_in,
                              void* d_out, int out_size, void* d_ws, size_t ws_size,
                              hipStream_t stream) {
    // inputs: 0=desc(unused) 1=nve 2=Wq 3=bq 4=Wk 5=bk 6=cls
    const float* nve = (const float*)d_in[1];
    const float* Wq  = (const float*)d_in[2];
    const float* bq  = (const float*)d_in[3];
    const float* Wk  = (const float*)d_in[4];
    const float* bk  = (const float*)d_in[5];
    const float* cls = (const float*)d_in[6];

    float* out = (float*)d_out;

    // masks always at ws[0..16KB)
    unsigned long long* mem = (unsigned long long*)d_ws;   // B*S = 2048 u64

    // q/kT staging: prefer d_ws (+64KB offset) if it fits; else stage inside
    // out's b=31 region (then C must gated-dense-rewrite b=31's rows).
    const size_t need = 64 * 1024 + 2 * Q_ELEMS * sizeof(float);  // ~8.6 MB
    const bool ws_ok = (ws_size >= need);

    float* q  = ws_ok ? (float*)((char*)d_ws + 64 * 1024) : out + STAGE_BASE;
    float* kT = q + Q_ELEMS;
    const int nf4     = ws_ok ? OUT0_F4 : (int)(STAGE_BASE / 4);
    const int dense31 = ws_ok ? 0 : 1;

    kA_gemm_fill<<<NG_GEMM + NG_FILL, 256, 0, stream>>>(nve, Wq, bq, Wk, bk,
                                                        q, kT, out, nf4);
    kB_attn<<<N3_ROWS, 128, 0, stream>>>(q, kT, mem);
    kC_finish<<<N3_ROWS + N3_TAIL, 256, 0, stream>>>(nve, cls, mem, out, dense31);
}

// Round 10
// 109.545 us; speedup vs baseline: 1.2842x; 1.2842x over previous
//
#include <hip/hip_runtime.h>
#include <math.h>

// Problem constants (fixed by setup_inputs)
constexpr int B = 32;
constexpr int N = 65;    // seq_len + 1
constexpr int D = 512;
constexpr int S = 64;    // N - 1
constexpr int M = B * N; // 2080 rows for the QK projection GEMM

// out0 layout: [B, S, S+1, D] = 68,157,440 floats. The b=31 block
// (last 2,129,920 floats) is EXACTLY q (M*D) + kT (B*D*N) — we stage q/kT
// there, zero-fill b<31 concurrently, and densely rewrite b=31 at the end.
constexpr size_t OUT0_ELEMS = (size_t)B * S * (S + 1) * D;       // 68,157,440
constexpr size_t Q_ELEMS    = (size_t)M * D;                      // 1,064,960
constexpr size_t KT_ELEMS   = (size_t)B * D * N;                  // 1,064,960
constexpr size_t STAGE_BASE = OUT0_ELEMS - Q_ELEMS - KT_ELEMS;    // == b31 start
constexpr int ZF4 = (int)(STAGE_BASE / 4);                        // 16,506,880 float4 zeros

// K1 grid split
constexpr int NG_GEMM = 528;   // 33 m-tiles x 8 n-tiles x 2 matrices
constexpr int NG_FILL = 1536;
// K4 grid split
constexpr int NC = (B - 1) * S;            // 1984 scatter blocks (b<31)
constexpr int NA = 1040;                   // b31 dense fill: 1040*512 f4 = 532,480
constexpr int NB = 130;                    // leader+member: 130*256 f4 = 33,280

// ---------------------------------------------------------------------------
// K1: fused projection GEMM (q = nve@Wq^T+bq row-major; kT[b][d][n]) plus
// zero-fill of out0[b<31]. GEMM: 64x64 tile, BK=32, 256 threads, 4x4
// microtile, q and k share the A (nve) tile.
// ---------------------------------------------------------------------------
__global__ __launch_bounds__(256) void k1_gemm_fill(
    const float* __restrict__ nve, const float* __restrict__ Wq,
    const float* __restrict__ bq, const float* __restrict__ Wk,
    const float* __restrict__ bk, float* __restrict__ out)
{
    __shared__ float As[32][68];
    __shared__ float Qs[32][68];
    __shared__ float Ks[32][68];

    const int gid = blockIdx.x;
    const int tid = threadIdx.x;

    if (gid < NG_GEMM) {
        const int mat = gid >= (NG_GEMM / 2);
        const int t   = mat ? gid - NG_GEMM / 2 : gid;
        const int bm  = (t % 33) * 64;
        const int bn  = (t / 33) * 64;
        const float* W    = mat ? Wk : Wq;
        const float* bias = mat ? bk : bq;

        float* q  = out + STAGE_BASE;            // [M][D]
        float* kT = q + Q_ELEMS;                 // [B][D][N]

        const int tr = tid / 16;
        const int tc = tid % 16;
        float acc[4][4] = {};

        for (int k0 = 0; k0 < D; k0 += 32) {
            const int r  = tid / 8;
            const int c4 = (tid % 8) * 4;
            #pragma unroll
            for (int p = 0; p < 2; ++p) {
                const int rr = p * 32 + r;
                const int gm = bm + rr;
                float4 v = make_float4(0.f, 0.f, 0.f, 0.f);
                if (gm < M) v = *(const float4*)&nve[(size_t)gm * D + k0 + c4];
                As[c4 + 0][rr] = v.x; As[c4 + 1][rr] = v.y;
                As[c4 + 2][rr] = v.z; As[c4 + 3][rr] = v.w;
                float4 w = *(const float4*)&W[(size_t)(bn + rr) * D + k0 + c4];
                Qs[c4 + 0][rr] = w.x; Qs[c4 + 1][rr] = w.y;
                Qs[c4 + 2][rr] = w.z; Qs[c4 + 3][rr] = w.w;
            }
            __syncthreads();

            #pragma unroll
            for (int kk = 0; kk < 32; ++kk) {
                float a[4], w[4];
                #pragma unroll
                for (int u = 0; u < 4; ++u) a[u] = As[kk][tr * 4 + u];
                #pragma unroll
                for (int u = 0; u < 4; ++u) w[u] = Qs[kk][tc * 4 + u];
                #pragma unroll
                for (int i = 0; i < 4; ++i)
                    #pragma unroll
                    for (int j = 0; j < 4; ++j)
                        acc[i][j] += a[i] * w[j];
            }
            __syncthreads();
        }

        #pragma unroll
        for (int i = 0; i < 4; ++i) {
            const int gm = bm + tr * 4 + i;
            if (gm >= M) continue;
            const int b = gm / N;
            const int n = gm % N;
            if (mat == 0) {
                float4 v;
                v.x = acc[i][0] + bias[bn + tc * 4 + 0];
                v.y = acc[i][1] + bias[bn + tc * 4 + 1];
                v.z = acc[i][2] + bias[bn + tc * 4 + 2];
                v.w = acc[i][3] + bias[bn + tc * 4 + 3];
                *(float4*)&q[(size_t)gm * D + bn + tc * 4] = v;
            } else {
                #pragma unroll
                for (int j = 0; j < 4; ++j) {
                    const int gd = bn + tc * 4 + j;
                    kT[(size_t)b * D * N + (size_t)gd * N + n] = acc[i][j] + bias[gd];
                }
            }
        }
    } else {
        // zero-fill out0[b < 31] (float4 grid-stride)
        const float4 z = make_float4(0.f, 0.f, 0.f, 0.f);
        float4* o4 = (float4*)out;
        const int nthr = NG_FILL * 256;
        for (int f = (gid - NG_GEMM) * 256 + tid; f < ZF4; f += nthr)
            o4[f] = z;
    }
}

// NOTE vs the original R2 source: K1 above keeps the 3-tile structure but the
// Ks tile was unused duplication in R2 only in the sense that mat selects W;
// to stay byte-equivalent in BEHAVIOR with R2's separate q/k blocks (528
// blocks, each computing ONE matrix), we load only the selected W into Qs.
// LDS footprint stays 26.1 KB (3 arrays declared) exactly as R2 declared.

// ---------------------------------------------------------------------------
// K2: per (b,i), i in 1..64: scores over 65 cols (diag of [1:,1:] zeroed
// pre-softmax), softmax, member bits = (prob > 0.05) | eye -> 64-bit mask.
// One block of 128 threads per row (R2-proven).
// ---------------------------------------------------------------------------
__global__ __launch_bounds__(128) void k2_attn(
    const float* __restrict__ out, unsigned long long* __restrict__ mem)
{
    const float* q  = out + STAGE_BASE;
    const float* kT = q + Q_ELEMS;

    const int bi = blockIdx.x;     // 0..B*S-1
    const int b = bi / S;
    const int r = bi % S;
    const int i = r + 1;
    const int t = threadIdx.x;

    __shared__ float qrow[D];
    __shared__ float sc[N];

    *(float4*)&qrow[t * 4] = *(const float4*)&q[((size_t)b * N + i) * D + t * 4];
    __syncthreads();

    if (t < N) {
        const float* kp = &kT[(size_t)b * D * N];
        float acc = 0.f;
        for (int e = 0; e < D; ++e) acc += qrow[e] * kp[(size_t)e * N + t];
        float s = acc * 0.044194173824159216f;  // 1/sqrt(512)
        if (t == i) s = 0.f;
        sc[t] = s;
    }
    __syncthreads();

    if (t < 64) {
        float mx = -INFINITY;
        for (int j = 0; j < N; ++j) mx = fmaxf(mx, sc[j]);
        float sum = 0.f;
        for (int j = 0; j < N; ++j) sum += expf(sc[j] - mx);
        const float p = expf(sc[t + 1] - mx) / sum;
        const bool bit = (p > 0.05f) || (t + 1 == i);
        unsigned long long mask = __ballot(bit);
        if (t == 0) mem[bi] = mask;
    }
}

// ---------------------------------------------------------------------------
// K3: greedy sequential clustering — one thread per batch.
// ---------------------------------------------------------------------------
__global__ void k3_cluster(const unsigned long long* __restrict__ mem,
                           unsigned long long* __restrict__ sel,
                           unsigned long long* __restrict__ lead)
{
    const int b = threadIdx.x;
    if (b >= B) return;
    unsigned long long used = 0ull, lb = 0ull;
    for (int i = 0; i < S; ++i) {
        const unsigned long long row = mem[b * S + i];
        const bool active = !((used >> i) & 1ull);
        const unsigned long long sl = active ? row : 0ull;
        used |= sl;
        lb |= (unsigned long long)active << i;
        sel[b * S + i] = sl;
    }
    lead[b] = lb;
}

// ---------------------------------------------------------------------------
// K4: (C) scatter nonzero rows for b<31; (A) dense bit-gated fill of the
// b=31 block (overwrites the q/kT staging); (B) leader/member outputs.
// ---------------------------------------------------------------------------
__global__ __launch_bounds__(256) void k4_finish(
    const float* __restrict__ nve, const float* __restrict__ cls,
    const unsigned long long* __restrict__ sel,
    const unsigned long long* __restrict__ lead,
    float* __restrict__ out)
{
    const int gid = blockIdx.x;
    const int t = threadIdx.x;

    if (gid < NC) {
        // scatter for b in [0,31): one block per (b,i) row
        const int b = gid / S;
        const int i = gid % S;
        const unsigned long long lb = lead[b];
        const unsigned long long sb = sel[b * S + i];
        const int h = t >> 7;          // 0/1: two columns in parallel
        const int tt = t & 127;        // f4 index within a 512-float slot
        float4* slot0 = (float4*)(out + (((size_t)b * S + i) * (S + 1)) * D);
        for (int s = h; s <= S; s += 2) {
            bool on = (s == 0) ? ((lb >> i) & 1ull) : ((sb >> (s - 1)) & 1ull);
            if (!on) continue;
            const float* src = (s == 0) ? cls : &nve[((size_t)b * N + s) * D];
            slot0[(size_t)s * 128 + tt] = ((const float4*)src)[tt];
        }
    } else if (gid < NC + NA) {
        // dense fill of b=31 region: 532,480 f4, 512 per block
        const int ablk = gid - NC;
        const unsigned long long lb = lead[B - 1];
        float4* base4 = (float4*)out + STAGE_BASE / 4;
        #pragma unroll
        for (int u = 0; u < 2; ++u) {
            const int f = ablk * 512 + u * 256 + t;
            const int d4 = f & 127;
            const int slot = f >> 7;         // 0..4159
            const int s = slot % (S + 1);
            const int i = slot / (S + 1);
            bool on;
            const float* src;
            if (s == 0) {
                on = (lb >> i) & 1ull;
                src = &cls[d4 * 4];
            } else {
                on = (sel[(B - 1) * S + i] >> (s - 1)) & 1ull;
                src = &nve[((size_t)(B - 1) * N + s) * D + d4 * 4];
            }
            float4 v = make_float4(0.f, 0.f, 0.f, 0.f);
            if (on) v = *(const float4*)src;
            base4[f] = v;
        }
    } else {
        // leader [B,S] then member [B,S,S] floats, f4-stored
        const int f = (gid - NC - NA) * 256 + t;   // f4 index
        float* tail = out + OUT0_ELEMS;
        float4 v;
        #pragma unroll
        for (int c = 0; c < 4; ++c) {
            const int idx = f * 4 + c;
            float x;
            if (idx < B * S) {
                x = (float)((lead[idx / S] >> (idx % S)) & 1ull);
            } else {
                const int m = idx - B * S;   // < B*S*S
                const int b = m / (S * S);
                const int rem = m % (S * S);
                x = (float)((sel[b * S + rem / S] >> (rem % S)) & 1ull);
            }
            ((float*)&v)[c] = x;
        }
        *(float4*)&tail[(size_t)f * 4] = v;
    }
}

extern "C" void kernel_launch(void* const* d_in, const int* in_sizes, int n_in,
                              void* d_out, int out_size, void* d_ws, size_t ws_size,
                              hipStream_t stream) {
    // inputs: 0=desc(unused) 1=nve 2=Wq 3=bq 4=Wk 5=bk 6=cls
    const float* nve = (const float*)d_in[1];
    const float* Wq  = (const float*)d_in[2];
    const float* bq  = (const float*)d_in[3];
    const float* Wk  = (const float*)d_in[4];
    const float* bk  = (const float*)d_in[5];
    const float* cls = (const float*)d_in[6];

    float* out = (float*)d_out;

    // small bitmask scratch in d_ws (~33 KB)
    unsigned long long* mem  = (unsigned long long*)d_ws;       // B*S
    unsigned long long* sel  = mem + B * S;                     // B*S
    unsigned long long* lead = sel + B * S;                     // B

    k1_gemm_fill<<<NG_GEMM + NG_FILL, 256, 0, stream>>>(nve, Wq, bq, Wk, bk, out);
    k2_attn<<<B * S, 128, 0, stream>>>(out, mem);
    k3_cluster<<<1, 64, 0, stream>>>(mem, sel, lead);
    k4_finish<<<NC + NA + NB, 256, 0, stream>>>(nve, cls, sel, lead, out);
}